// Round 9
// baseline (28173.245 us; speedup 1.0000x reference)
//
#include <hip/hip_runtime.h>
#include <stdint.h>

// SPINN thin-stack TreeLSTM, MI355X, round 9: serial-K minimization.
// 128 pairs x 2 blocks (512 thr, 8 waves, 1 blk/CU via 90KB LDS pad).
// Wave kg owns 40 K-rows: 24 of [0,192) + 8 own-hr (phase A, no t-1 dep
// beyond own block) + 8 partner-hr (serial tail, via tagged ring + readlane,
// no LDS/barrier). Exchange: ring[4] of u64 {h,tag} - single-flight,
// optimistic load before phase A, validated after; lanes 0/8 always
// validate => per-step watermark gives timing-free happens-before for all
// plain h/c reads <= t-1. W: 160 floats in AGPRs (explicit accvgpr asm),
// 40 serial floats in pinned VGPRs. 2 barriers/step.

#define D    512
#define HD   128
#define LD   64
#define NTHR 512
#define GPR  328

typedef unsigned long long u64t;

#define AREAD(dst, src)  asm volatile("v_accvgpr_read_b32 %0, %1" : "=v"(dst) : "a"(src))
#define AWRITE(dst, src) asm volatile("v_accvgpr_write_b32 %0, %1" : "=a"(dst) : "v"(src))

__device__ __forceinline__ float sigf(float x){ return 1.0f/(1.0f+__expf(-x)); }
__device__ __forceinline__ float tanh_(float x){ return 1.0f-2.0f/(__expf(2.0f*x)+1.0f); }
__device__ __forceinline__ u64t gld64(const void* p){
  return __hip_atomic_load((const u64t*)p, __ATOMIC_RELAXED, __HIP_MEMORY_SCOPE_AGENT);
}
__device__ __forceinline__ void gst32(float* p, float v){
  __hip_atomic_store(p, v, __ATOMIC_RELAXED, __HIP_MEMORY_SCOPE_AGENT);
}
__device__ __forceinline__ void gst64(u64t* p, u64t v){
  __hip_atomic_store(p, v, __ATOMIC_RELAXED, __HIP_MEMORY_SCOPE_AGENT);
}

__global__ __launch_bounds__(NTHR,1) void spinn_kernel(
    const int* __restrict__ trans, const int* __restrict__ labels,
    const float* __restrict__ emb, const float* __restrict__ W,
    const float* __restrict__ bias, const float* __restrict__ leaf,
    float* __restrict__ out, u64t* __restrict__ ringu,
    float* __restrict__ hP, float* __restrict__ cP)
{
  const int bid = blockIdx.x;
  const int g2 = bid>>1, sl = bid&1, ps = sl^1;
  const int gb0 = g2*2;
  const int tid = threadIdx.x;
  const int kg = tid>>6, lane = tid&63;
  const int cq = lane;

  __shared__ __align__(16) float xs[2][2][320];
  __shared__ __align__(16) float gpq[16][GPR];
  __shared__ float bsl[320];
  __shared__ float lshd[HD];
  __shared__ float clb[2][2][64];
  __shared__ uint8_t mS[D][2];
  __shared__ unsigned short liA[D][2];
  __shared__ unsigned short stk_[2][D];
  __shared__ float padL[14336];   // pad to ~90KB: force 1 block/CU

  const int gq = (cq>>4)*128 + sl*64 + ((cq*4)&63);  // 4 quad cols (gates 0-3)
  const int gu = 512 + sl*64 + cq;                   // u-gate col

  // --- W: 32 A-rows -> AGPR (128 quad + 32 u); 8 serial rows -> VGPR ---
  float wa[160];
#pragma unroll
  for (int j=0;j<32;++j){
    int k = (j<24) ? (kg*24 + j) : (192 + sl*64 + kg*8 + (j-24));
    const float* wp = W + (size_t)k*640;
    float4 w4 = *(const float4*)(wp + gq);
    AWRITE(wa[4*j+0], w4.x); AWRITE(wa[4*j+1], w4.y);
    AWRITE(wa[4*j+2], w4.z); AWRITE(wa[4*j+3], w4.w);
    float wu = wp[gu];
    AWRITE(wa[128+j], wu);
  }
  float wsx[8], wsy[8], wsz[8], wsw[8], wsu[8];
#pragma unroll
  for (int i=0;i<8;++i){
    int k = 192 + ps*64 + kg*8 + i;
    const float* wp = W + (size_t)k*640;
    float4 w4 = *(const float4*)(wp + gq);
    wsx[i]=w4.x; wsy[i]=w4.y; wsz[i]=w4.z; wsw[i]=w4.w; wsu[i]=wp[gu];
    asm volatile("" : "+v"(wsx[i]), "+v"(wsy[i]), "+v"(wsz[i]),
                      "+v"(wsw[i]), "+v"(wsu[i]));
  }

  if (tid < 320){
    int c = tid;
    int gc = (c < 256) ? ((c>>6)*128 + sl*64 + (c&63)) : (512 + sl*64 + (c-256));
    bsl[c] = bias[gc];
  }
  if (tid < HD) lshd[tid] = leaf[tid];
  if (tid < 2){   // precompute (mask, li); ri == t-1 always on a reduce
    int b = tid, p = 0;
    for (int t=0;t<D;++t){
      int m = trans[t*256 + gb0 + b];
      int li = 0;
      if (m) li = stk_[b][p-2];
      mS[t][b] = (uint8_t)m; liA[t][b] = (unsigned short)li;
      int np = p - 2*m; stk_[b][np] = (unsigned short)t; p = np+1;
    }
  }
  __syncthreads();

  // leaf values for the serial slice + LDS-pad opacity touch
  float lfs[8];
#pragma unroll
  for (int i=0;i<8;++i) lfs[i] = lshd[ps*64 + kg*8 + i];
  padL[(tid*29)&14335] = lshd[tid&127];

  // prefill xs[0]: emb + leaf (mask==0 at t=0 by schedule construction)
  for (int idx = tid; idx < 640; idx += NTHR){
    int b = (idx >= 320) ? 1 : 0;
    int r = idx - b*320;
    if (r < 64){
      int row = labels[gb0 + b];
      xs[0][b][r] = emb[(size_t)row*LD + r];
    } else {
      xs[0][b][r] = lshd[(r-64)&127];
    }
  }
  __syncthreads();
  if (padL[(tid*31)&14335] == 3.25e18f) xs[0][0][0] += 1.f;  // opaque: keep pad

  float ccprev = 0.f;

  for (int t=0;t<D;++t){
    const int cur = t&1, nxt = cur^1;

    // ---- optimistic ring load (partner h[t-1] serial slice) ----
    u64t rv = 0; const u64t* rp = nullptr; bool need = false;
    if (t > 0 && lane < 16){
      int lb = lane>>3, kk = lane&7;
      need = (mS[t][lb] != 0) || (kk == 0);   // kk==0: watermark lanes
      rp = ringu + ((((size_t)((t-1)&3)*128 + (size_t)g2)*2 + ps)*128
                    + lb*64 + kg*8 + kk);
      if (need) rv = gld64(rp);
    }

    // ---- phase A: 32 non-serial K-rows (AGPR W, LDS broadcast x) ----
    float4 a0 = {0.f,0.f,0.f,0.f}, a1 = {0.f,0.f,0.f,0.f};
    float u0 = 0.f, u1 = 0.f;
#pragma unroll
    for (int j4=0;j4<8;++j4){
      int r0 = (j4<6) ? (kg*24 + j4*4) : (192 + sl*64 + kg*8 + (j4-6)*4);
      float4 x0 = *(const float4*)&xs[cur][0][r0];
      float4 x1 = *(const float4*)&xs[cur][1][r0];
      float xa0[4]={x0.x,x0.y,x0.z,x0.w}, xa1[4]={x1.x,x1.y,x1.z,x1.w};
#pragma unroll
      for (int jj=0;jj<4;++jj){
        int j = j4*4+jj;
        float w0,w1,w2,w3,wu;
        AREAD(w0, wa[4*j+0]); AREAD(w1, wa[4*j+1]);
        AREAD(w2, wa[4*j+2]); AREAD(w3, wa[4*j+3]);
        AREAD(wu, wa[128+j]);
        a0.x=__builtin_fmaf(w0,xa0[jj],a0.x); a0.y=__builtin_fmaf(w1,xa0[jj],a0.y);
        a0.z=__builtin_fmaf(w2,xa0[jj],a0.z); a0.w=__builtin_fmaf(w3,xa0[jj],a0.w);
        a1.x=__builtin_fmaf(w0,xa1[jj],a1.x); a1.y=__builtin_fmaf(w1,xa1[jj],a1.y);
        a1.z=__builtin_fmaf(w2,xa1[jj],a1.z); a1.w=__builtin_fmaf(w3,xa1[jj],a1.w);
        u0=__builtin_fmaf(wu,xa0[jj],u0);     u1=__builtin_fmaf(wu,xa1[jj],u1);
      }
    }

    // ---- validate ring (tag == t-1), retry if partner behind ----
    if (t > 0){
      const unsigned want = (unsigned)(t-1);
      int it = 0;
      for (;;){
        bool ok = (!need) || ((unsigned)(rv>>32) == want);
        if (__all(ok ? 1 : 0)) break;
        if (++it > (1<<20)) break;   // safety: hang -> wrong answer
        __builtin_amdgcn_s_sleep(1);
        if (need && (unsigned)(rv>>32) != want) rv = gld64(rp);
      }
    }

    // ---- serial tail: 8 partner-hr K-rows via readlane (no LDS) ----
    if (mS[t][0]){
#pragma unroll
      for (int kk=0;kk<8;++kk){
        float xv = __int_as_float(__builtin_amdgcn_readlane((int)rv, kk));
        a0.x=__builtin_fmaf(wsx[kk],xv,a0.x); a0.y=__builtin_fmaf(wsy[kk],xv,a0.y);
        a0.z=__builtin_fmaf(wsz[kk],xv,a0.z); a0.w=__builtin_fmaf(wsw[kk],xv,a0.w);
        u0=__builtin_fmaf(wsu[kk],xv,u0);
      }
    } else {
#pragma unroll
      for (int kk=0;kk<8;++kk){
        float xv = lfs[kk];
        a0.x=__builtin_fmaf(wsx[kk],xv,a0.x); a0.y=__builtin_fmaf(wsy[kk],xv,a0.y);
        a0.z=__builtin_fmaf(wsz[kk],xv,a0.z); a0.w=__builtin_fmaf(wsw[kk],xv,a0.w);
        u0=__builtin_fmaf(wsu[kk],xv,u0);
      }
    }
    if (mS[t][1]){
#pragma unroll
      for (int kk=0;kk<8;++kk){
        float xv = __int_as_float(__builtin_amdgcn_readlane((int)rv, 8+kk));
        a1.x=__builtin_fmaf(wsx[kk],xv,a1.x); a1.y=__builtin_fmaf(wsy[kk],xv,a1.y);
        a1.z=__builtin_fmaf(wsz[kk],xv,a1.z); a1.w=__builtin_fmaf(wsw[kk],xv,a1.w);
        u1=__builtin_fmaf(wsu[kk],xv,u1);
      }
    } else {
#pragma unroll
      for (int kk=0;kk<8;++kk){
        float xv = lfs[kk];
        a1.x=__builtin_fmaf(wsx[kk],xv,a1.x); a1.y=__builtin_fmaf(wsy[kk],xv,a1.y);
        a1.z=__builtin_fmaf(wsz[kk],xv,a1.z); a1.w=__builtin_fmaf(wsw[kk],xv,a1.w);
        u1=__builtin_fmaf(wsu[kk],xv,u1);
      }
    }

    *(float4*)&gpq[kg*2+0][cq*4] = a0;
    *(float4*)&gpq[kg*2+1][cq*4] = a1;
    gpq[kg*2+0][256+cq] = u0;
    gpq[kg*2+1][256+cq] = u1;
    __syncthreads();

    // ---- cell (waves 0-1) || prefetch t+1 (waves 2-5) ----
    if (tid < 128){
      const int b = tid>>6, dl = tid&63, gd = sl*64+dl;
      const int m = mS[t][b];
      float s0=0.f,s1=0.f,s2=0.f,s3=0.f,s4=0.f;
#pragma unroll
      for (int kk=0;kk<8;++kk){
        const float* gr = gpq[kk*2+b];
        s0 += gr[dl]; s1 += gr[64+dl]; s2 += gr[128+dl];
        s3 += gr[192+dl]; s4 += gr[256+dl];
      }
      s0 += bsl[dl]; s1 += bsl[64+dl]; s2 += bsl[128+dl];
      s3 += bsl[192+dl]; s4 += bsl[256+dl];
      float cl_ = m ? clb[cur][b][dl] : lshd[gd];
      float cr_ = m ? ccprev : lshd[gd];       // ri == t-1: own prev c
      float cc = sigf(s0)*tanh_(s4) + sigf(s1)*cl_ + sigf(s2)*cr_;
      float hh = sigf(s3)*tanh_(cc);
      ccprev = cc;
      size_t po = (((size_t)t*128 + g2)*2 + sl)*128 + b*64 + dl;
      gst32(hP + po, hh);
      gst32(cP + po, cc);
      if (t == D-1){
        out[(size_t)(gb0+b)*HD + gd] = cc;
        out[(size_t)256*HD + (size_t)(gb0+b)*HD + gd] = hh;
      } else {
        xs[nxt][b][192+sl*64+dl] = mS[t+1][b] ? hh : lshd[gd];  // own-hr t+1
      }
      __asm__ volatile("s_waitcnt vmcnt(0)" ::: "memory");  // drain plain
      u64t pv = ((u64t)(unsigned)t << 32) | (u64t)__float_as_uint(hh);
      gst64(ringu + ((((size_t)(t&3)*128 + (size_t)g2)*2 + sl)*128 + b*64 + dl), pv);
    } else if (t+1 < D){
      if (kg == 2){            // emb for t+1
        int b = lane>>5, jj = lane&31;
        int row = labels[(t+1)*256 + gb0 + b];
        float2 ev = *(const float2*)(emb + (size_t)row*LD + jj*2);
        xs[nxt][b][jj*2] = ev.x; xs[nxt][b][jj*2+1] = ev.y;
      } else if (kg == 3 || kg == 4){   // hl (full 128 dims), b = kg-3
        int b = kg - 3;
        int gd = lane*2;
        if (mS[t+1][b]){
          int li = liA[t+1][b];
          size_t po = (((size_t)li*128 + g2)*2 + (gd>>6))*128 + b*64 + (gd&63);
          u64t hv = gld64(hP + po);
          union{u64t u; float f[2];} w; w.u = hv;
          xs[nxt][b][64+gd] = w.f[0]; xs[nxt][b][64+gd+1] = w.f[1];
        } else {
          xs[nxt][b][64+gd] = lshd[gd]; xs[nxt][b][64+gd+1] = lshd[gd+1];
        }
      } else if (kg == 5){     // cl (own 64 dims x 2 b)
        int b = lane>>5, dl2 = (lane&31)*2;
        if (mS[t+1][b]){
          int li = liA[t+1][b];
          size_t po = (((size_t)li*128 + g2)*2 + sl)*128 + b*64 + dl2;
          u64t cv = gld64(cP + po);
          union{u64t u; float f[2];} w; w.u = cv;
          clb[nxt][b][dl2] = w.f[0]; clb[nxt][b][dl2+1] = w.f[1];
        } else {
          clb[nxt][b][dl2]   = lshd[sl*64+dl2];
          clb[nxt][b][dl2+1] = lshd[sl*64+dl2+1];
        }
      }
    }
    __syncthreads();
  }
}

extern "C" void kernel_launch(void* const* d_in, const int* in_sizes, int n_in,
                              void* d_out, int out_size, void* d_ws, size_t ws_size,
                              hipStream_t stream) {
  (void)in_sizes; (void)n_in; (void)out_size; (void)ws_size;
  const int*   trans  = (const int*)d_in[0];
  const int*   labels = (const int*)d_in[1];
  const float* emb    = (const float*)d_in[2];
  const float* W      = (const float*)d_in[3];
  const float* bias   = (const float*)d_in[4];
  const float* leaf   = (const float*)d_in[5];
  float* out = (float*)d_out;

  // ws: [0,1MB) ring (depth-4 u64 {h,tag}; tags exact-match t -> 0xAA poison
  //     never validates, no init needed) | [2MB,~69MB) hP | [70MB,~137MB) cP
  uint8_t* ws = (uint8_t*)d_ws;
  u64t*  ringu = (u64t*)ws;
  float* hP = (float*)(ws + ((size_t)2<<20));
  float* cP = (float*)(ws + ((size_t)70<<20));

  spinn_kernel<<<dim3(256), dim3(NTHR), 0, stream>>>(
      trans, labels, emb, W, bias, leaf, out, ringu, hP, cP);
}

// Round 10
// 5279.257 us; speedup vs baseline: 5.3366x; 5.3366x over previous
//
#include <hip/hip_runtime.h>
#include <stdint.h>

// SPINN thin-stack TreeLSTM, MI355X, round 10 = round 6 + LDS W-cache.
// R9 post-mortem: W-in-registers is impossible (unified VGPR+AGPR budget
// 256/thread at 8 waves; every variant pins VGPR=128; AGPR attempt spilled
// to scratch -> 28.5 GB FETCH). R6-R8 all ~2.0ms = 9600 cyc/step, of which
// ~6400 = per-step 400KB W re-stream from L2 (compiler remat).
// R10: stage 12 of each wave's 40 K-rows (96 rows x 320 block-cols =
// 122.9 KB) into static LDS once; GEMM reads those via ds_read (separate
// pipe, overlaps the remaining 287KB VMEM stream). Sync structure is R6's
// proven pairwise fan-in-2 (tags+records, 3 barriers). LDS ~157KB -> 1 blk/CU.

#define D     512
#define HD    128
#define LD    64
#define NTHR  512
#define GPR   328   // gp row stride (floats)
#define LROWS 12    // LDS-cached K-rows per wave (of 40)

typedef unsigned long long u64t;

__device__ __forceinline__ float sigf(float x){ return 1.0f/(1.0f+__expf(-x)); }
__device__ __forceinline__ float tanh_(float x){ return 1.0f-2.0f/(__expf(2.0f*x)+1.0f); }
__device__ __forceinline__ u64t gld64(const float* p){
  return __hip_atomic_load((const u64t*)p, __ATOMIC_RELAXED, __HIP_MEMORY_SCOPE_AGENT);
}
__device__ __forceinline__ u64t gld64u(const unsigned* p){
  return __hip_atomic_load((const u64t*)p, __ATOMIC_RELAXED, __HIP_MEMORY_SCOPE_AGENT);
}
__device__ __forceinline__ void gst32(float* p, float v){
  __hip_atomic_store(p, v, __ATOMIC_RELAXED, __HIP_MEMORY_SCOPE_AGENT);
}
__device__ __forceinline__ void gsttag(unsigned* p, unsigned v){
  __hip_atomic_store(p, v, __ATOMIC_RELAXED, __HIP_MEMORY_SCOPE_AGENT);
}

__global__ __launch_bounds__(NTHR,1) void spinn_kernel(
    const int* __restrict__ trans, const int* __restrict__ labels,
    const float* __restrict__ emb, const float* __restrict__ W,
    const float* __restrict__ bias, const float* __restrict__ leaf,
    float* __restrict__ out, unsigned* __restrict__ tags,
    float* __restrict__ rec, float* __restrict__ cown)
{
  const int bid = blockIdx.x;
  const int g2 = bid>>1, sl = bid&1, ps = sl^1;
  const int gb0 = g2*2;
  const int tid = threadIdx.x;
  const int kg = tid>>6, lane = tid&63;
  const int cq = lane;

  __shared__ __align__(16) float wlds[8*LROWS*320];  // 122,880 B: W rows cache
  __shared__ __align__(16) float xs[2][2][320];      // [buf][b][k]
  __shared__ __align__(16) float gpq[16][GPR];       // [(kg*2+b)][col]
  __shared__ float bsl[320];
  __shared__ float lshd[HD];
  __shared__ float clb[2][2][64];
  __shared__ uint8_t mS[D][2];
  __shared__ short liA[D][2];
  __shared__ unsigned short stk_[2][D];

  const int gq = (cq>>4)*128 + sl*64 + ((cq*4)&63);  // 4 quad cols (gates 0-3)
  const int gu = 512 + sl*64 + cq;                   // u-gate col

  if (tid < 320){
    int c = tid;
    int gc = (c < 256) ? ((c>>6)*128 + sl*64 + (c&63)) : (512 + sl*64 + (c-256));
    bsl[c] = bias[gc];
  }
  if (tid < HD) lshd[tid] = leaf[tid];
  if (tid < 2){   // precompute (mask, li); ri == t-1 always on a reduce
    int b = tid, p = 0;
    for (int t=0;t<D;++t){
      int m = trans[t*256 + gb0 + b];
      short li = 0;
      if (m) li = (short)stk_[b][p-2];
      mS[t][b] = (uint8_t)m; liA[t][b] = li;
      int np = p - 2*m; stk_[b][np] = (unsigned short)t; p = np+1;
    }
  }
  __syncthreads();

  // --- fill W LDS cache: row r (wave r/LROWS, sub r%LROWS) = global k-row ---
  // local col c: c<256 -> gate (c>>6), dim sl*64+(c&63); c>=256 -> u col.
  for (int idx = tid; idx < 8*LROWS*320; idx += NTHR){
    int r = idx / 320, c = idx - r*320;
    int k = (r / LROWS)*40 + (r % LROWS);
    int gc = (c < 256) ? ((c>>6)*128 + sl*64 + (c&63)) : (512 + sl*64 + (c-256));
    wlds[idx] = W[(size_t)k*640 + gc];
  }

  // --- prefill xs[0]: emb(labels[0]) + leaf (mask(0)==0 by construction) ---
  for (int idx = tid; idx < 640; idx += NTHR){
    int b = (idx >= 320) ? 1 : 0;
    int r = idx - b*320;
    if (r < 64){
      int row = labels[gb0 + b];
      xs[0][b][r] = emb[(size_t)row*LD + r];
    } else {
      xs[0][b][r] = lshd[(r-64)&127];
    }
  }
  __syncthreads();

  auto gemm = [&](int cur){
    float4 a0 = {0.f,0.f,0.f,0.f}, a1 = {0.f,0.f,0.f,0.f};
    float u0 = 0.f, u1 = 0.f;
    // part 1: LROWS rows from LDS cache
#pragma unroll
    for (int j4=0;j4<LROWS/4;++j4){
      int k = kg*40 + j4*4;
      float4 x0 = *(const float4*)&xs[cur][0][k];   // broadcast
      float4 x1 = *(const float4*)&xs[cur][1][k];
      float xa0[4] = {x0.x,x0.y,x0.z,x0.w};
      float xa1[4] = {x1.x,x1.y,x1.z,x1.w};
#pragma unroll
      for (int jj=0;jj<4;++jj){
        const int r = kg*LROWS + j4*4 + jj;
        float4 w = *(const float4*)&wlds[r*320 + cq*4];
        float wu = wlds[r*320 + 256 + cq];
        a0.x = __builtin_fmaf(w.x, xa0[jj], a0.x);
        a0.y = __builtin_fmaf(w.y, xa0[jj], a0.y);
        a0.z = __builtin_fmaf(w.z, xa0[jj], a0.z);
        a0.w = __builtin_fmaf(w.w, xa0[jj], a0.w);
        a1.x = __builtin_fmaf(w.x, xa1[jj], a1.x);
        a1.y = __builtin_fmaf(w.y, xa1[jj], a1.y);
        a1.z = __builtin_fmaf(w.z, xa1[jj], a1.z);
        a1.w = __builtin_fmaf(w.w, xa1[jj], a1.w);
        u0 = __builtin_fmaf(wu, xa0[jj], u0);
        u1 = __builtin_fmaf(wu, xa1[jj], u1);
      }
    }
    // part 2: remaining rows streamed from global (L2-resident W)
#pragma unroll
    for (int j4=LROWS/4;j4<10;++j4){
      int k = kg*40 + j4*4;
      float4 x0 = *(const float4*)&xs[cur][0][k];
      float4 x1 = *(const float4*)&xs[cur][1][k];
      float xa0[4] = {x0.x,x0.y,x0.z,x0.w};
      float xa1[4] = {x1.x,x1.y,x1.z,x1.w};
#pragma unroll
      for (int jj=0;jj<4;++jj){
        const int kk = k + jj;
        float4 w = *(const float4*)(W + (size_t)kk*640 + gq);
        float wu = W[(size_t)kk*640 + gu];
        a0.x = __builtin_fmaf(w.x, xa0[jj], a0.x);
        a0.y = __builtin_fmaf(w.y, xa0[jj], a0.y);
        a0.z = __builtin_fmaf(w.z, xa0[jj], a0.z);
        a0.w = __builtin_fmaf(w.w, xa0[jj], a0.w);
        a1.x = __builtin_fmaf(w.x, xa1[jj], a1.x);
        a1.y = __builtin_fmaf(w.y, xa1[jj], a1.y);
        a1.z = __builtin_fmaf(w.z, xa1[jj], a1.z);
        a1.w = __builtin_fmaf(w.w, xa1[jj], a1.w);
        u0 = __builtin_fmaf(wu, xa0[jj], u0);
        u1 = __builtin_fmaf(wu, xa1[jj], u1);
      }
    }
    *(float4*)&gpq[kg*2+0][cq*4] = a0;
    *(float4*)&gpq[kg*2+1][cq*4] = a1;
    gpq[kg*2+0][256+cq] = u0;
    gpq[kg*2+1][256+cq] = u1;
  };

  float ccprev = 0.f;   // own c[t-1][b][dl] (cell threads only)

  for (int t=0;t<D;++t){
    const int cur = t&1, nxt = cur^1;

    // ---- P1: GEMM_A (waves 0-3) || prefetch t+1 (4-6) || hr spin+load (7) ---
    if (kg < 4){
      gemm(cur);
    } else if (kg == 4){
      if (t+1 < D){
        int b = lane>>5, jj = lane&31;
        int row = labels[(t+1)*256 + gb0 + b];
        float2 ev = *(const float2*)(emb + (size_t)row*LD + jj*2);
        xs[nxt][b][jj*2]   = ev.x;
        xs[nxt][b][jj*2+1] = ev.y;
      }
    } else if (kg == 5){
      if (t+1 < D){
        int b = lane>>5, jj = lane&31;
        int m1 = mS[t+1][b]; int li = liA[t+1][b];
        if (m1){
          if (li <= t-2){
            size_t ro = (((size_t)li*128+g2)*2 + sl)*128 + b*64 + jj*2;
            union{u64t u; float f[2];} h_, c_;
            h_.u = gld64(rec + ro);
            c_.u = gld64(cown + ro);
            xs[nxt][b][64+sl*64+jj*2]   = h_.f[0];
            xs[nxt][b][64+sl*64+jj*2+1] = h_.f[1];
            clb[nxt][b][jj*2]   = c_.f[0];
            clb[nxt][b][jj*2+1] = c_.f[1];
          }
          // li == t-1: cell@t-1 already wrote xs/clb from registers
        } else {
          xs[nxt][b][64+sl*64+jj*2]   = lshd[sl*64+jj*2];
          xs[nxt][b][64+sl*64+jj*2+1] = lshd[sl*64+jj*2+1];
          clb[nxt][b][jj*2]   = lshd[sl*64+jj*2];
          clb[nxt][b][jj*2+1] = lshd[sl*64+jj*2+1];
        }
      }
    } else if (kg == 6){
      if (t+1 < D){
        int b = lane>>5, jj = lane&31;
        int m1 = mS[t+1][b]; int li = liA[t+1][b];
        if (m1){
          if (li <= t-2){
            size_t ro = (((size_t)li*128+g2)*2 + ps)*128 + b*64 + jj*2;
            union{u64t u; float f[2];} h_;
            h_.u = gld64(rec + ro);
            xs[nxt][b][64+ps*64+jj*2]   = h_.f[0];
            xs[nxt][b][64+ps*64+jj*2+1] = h_.f[1];
          }
          // li == t-1: wave 7 writes it from the hr record
        } else {
          xs[nxt][b][64+ps*64+jj*2]    = lshd[ps*64+jj*2];
          xs[nxt][b][64+ps*64+jj*2+1]  = lshd[ps*64+jj*2+1];
          xs[nxt][b][192+ps*64+jj*2]   = lshd[ps*64+jj*2];
          xs[nxt][b][192+ps*64+jj*2+1] = lshd[ps*64+jj*2+1];
        }
      }
    } else { // kg == 7: partner h[t-1]
      if (t > 0){
        const unsigned* tp = tags + (((size_t)(t-1)*128+g2)*2 + ps)*16;
        u64t want = ((u64t)(unsigned)(t-1) << 32) | (unsigned)(t-1);
        int it = 0;
        while (gld64u(tp) != want){
          __builtin_amdgcn_s_sleep(1);
          if (++it > (1<<20)) break;   // safety: hang -> wrong answer
        }
        int b = lane>>5, jj = lane&31;
        size_t ro = (((size_t)(t-1)*128+g2)*2 + ps)*128 + lane*2;
        union{u64t u; float f[2];} h_;
        h_.u = gld64(rec + ro);
        if (mS[t][b]){
          xs[cur][b][192+ps*64+jj*2]   = h_.f[0];
          xs[cur][b][192+ps*64+jj*2+1] = h_.f[1];
        }
        if (t+1 < D && mS[t+1][b] && liA[t+1][b] == t-1){
          xs[nxt][b][64+ps*64+jj*2]   = h_.f[0];
          xs[nxt][b][64+ps*64+jj*2+1] = h_.f[1];
        }
      }
    }
    __syncthreads();

    // ---- P2: GEMM_B (waves 4-7) ----
    if (kg >= 4){ gemm(cur); }
    __syncthreads();

    // ---- P3: cell (2 waves) ----
    if (tid < 128){
      const int b = tid>>6, dl = tid&63, gd = sl*64+dl;
      const int m = mS[t][b];
      float s[5];
#pragma unroll
      for (int g=0; g<5; ++g){
        int c = (g<4) ? (g*64+dl) : (256+dl);
        float a = 0.f;
#pragma unroll
        for (int kk=0; kk<8; ++kk) a += gpq[kk*2+b][c];
        s[g] = a + bsl[c];
      }
      float cl_ = m ? clb[cur][b][dl] : lshd[gd];
      float cr_ = m ? ccprev : lshd[gd];            // ri == t-1: own prev c
      float cc = sigf(s[0])*tanh_(s[4]) + sigf(s[1])*cl_ + sigf(s[2])*cr_;
      float hh = sigf(s[3])*tanh_(cc);
      ccprev = cc;
      size_t ro = (((size_t)t*128 + g2)*2 + sl)*128 + b*64 + dl;
      gst32(rec + ro, hh);
      gst32(cown + ro, cc);
      if (t == D-1){
        out[(size_t)(gb0+b)*HD + gd] = cc;
        out[(size_t)256*HD + (size_t)(gb0+b)*HD + gd] = hh;
      } else {
        xs[nxt][b][192+gd] = mS[t+1][b] ? hh : lshd[gd];   // own hr for t+1
      }
      if (t+2 < D && mS[t+2][b] && liA[t+2][b] == t){
        xs[cur][b][64+gd]  = hh;    // own hl for t+2 (li==t case)
        clb[cur][b][dl]    = cc;    // own cl for t+2
      }
      __asm__ volatile("s_waitcnt vmcnt(0)" ::: "memory");  // wave-local drain
      if (dl == 0)
        gsttag(tags + (((size_t)t*128+g2)*2+sl)*16 + b, (unsigned)t);
    }
    __syncthreads();
  }
}

extern "C" void kernel_launch(void* const* d_in, const int* in_sizes, int n_in,
                              void* d_out, int out_size, void* d_ws, size_t ws_size,
                              hipStream_t stream) {
  (void)in_sizes; (void)n_in; (void)out_size; (void)ws_size;
  const int*   trans  = (const int*)d_in[0];
  const int*   labels = (const int*)d_in[1];
  const float* emb    = (const float*)d_in[2];
  const float* W      = (const float*)d_in[3];
  const float* bias   = (const float*)d_in[4];
  const float* leaf   = (const float*)d_in[5];
  float* out = (float*)d_out;

  // ws: [0,8MB) tags (64B per (t,g2,sl); 0xAA poison != any t<512 -> no init)
  //     [8MB,72MB) rec: h records | [72MB,136MB) cown: c records
  uint8_t* ws = (uint8_t*)d_ws;
  unsigned* tags = (unsigned*)ws;
  float* rec  = (float*)(ws + ((size_t)8<<20));
  float* cown = (float*)(ws + ((size_t)72<<20));

  spinn_kernel<<<dim3(256), dim3(NTHR), 0, stream>>>(
      trans, labels, emb, W, bias, leaf, out, tags, rec, cown);
}